// Round 1
// baseline (957.883 us; speedup 1.0000x reference)
//
#include <hip/hip_runtime.h>
#include <math.h>

#define NB      25200
#define THREADS 512
#define ITEMS   50           // 512*50 = 25600 >= 25200
#define NWAVE   (THREADS/64)
#define MAXOUT  100
#define CONF    0.25f
#define IOU_T   0.45f

__global__ __launch_bounds__(THREADS, 2)
void nms_kernel(const float* __restrict__ boxes,
                const float* __restrict__ scores,
                float* __restrict__ out)
{
    const int tid = threadIdx.x;

    // live scores (suppressed -> -inf); each thread only ever touches its own
    // slots (i = k*THREADS + tid), so no barriers are needed for s_sc.
    __shared__ float s_sc[THREADS * ITEMS];     // 100 KB (gfx950 LDS = 160 KB)
    __shared__ float red_v[NWAVE];
    __shared__ int   red_i[NWAVE];

    // per-thread box coords stay in registers (4*50 = 200 VGPR; capped at 256
    // by launch_bounds(512,2) -> 2 waves/SIMD, the 8-wave block fits one CU)
    float bx1[ITEMS], by1[ITEMS], bx2[ITEMS], by2[ITEMS];

    const float4* b4 = (const float4*)boxes;

    float lmax = -INFINITY;
    int   lidx = 0;

#pragma unroll
    for (int k = 0; k < ITEMS; ++k) {
        const int i = k * THREADS + tid;
        float  sc = -INFINITY;
        float4 bb = make_float4(0.f, 0.f, 0.f, 0.f);
        if (i < NB) {
            bb = b4[i];
            const float s = scores[i];
            sc = (s > CONF) ? s : -INFINITY;   // confidence filter == ref masking
        }
        bx1[k] = bb.x; by1[k] = bb.y; bx2[k] = bb.z; by2[k] = bb.w;
        s_sc[i] = sc;
        if (sc > lmax) { lmax = sc; lidx = i; }
    }

    for (int r = 0; r < MAXOUT; ++r) {
        // ---- block argmax of (score, index), ties -> lower index (stable argsort) ----
        float rv = lmax;
        int   ri = lidx;
#pragma unroll
        for (int off = 32; off >= 1; off >>= 1) {
            const float ov = __shfl_xor(rv, off);
            const int   oi = __shfl_xor(ri, off);
            if (ov > rv || (ov == rv && oi < ri)) { rv = ov; ri = oi; }
        }
        __syncthreads();                         // red[] reads from prev round done
        if ((tid & 63) == 0) { red_v[tid >> 6] = rv; red_i[tid >> 6] = ri; }
        __syncthreads();

        float wval = red_v[0];
        int   widx = red_i[0];
#pragma unroll
        for (int j = 1; j < NWAVE; ++j) {
            const float v  = red_v[j];
            const int   i2 = red_i[j];
            if (v > wval || (v == wval && i2 < widx)) { wval = v; widx = i2; }
        }

        const bool valid = (wval > -1e38f);      // finite <=> some box still alive
        if (!valid) {                            // uniform branch: all lanes agree
            if (tid == 0) {
                out[4*r+0] = 0.f; out[4*r+1] = 0.f;
                out[4*r+2] = 0.f; out[4*r+3] = 0.f;
                out[4*MAXOUT + r] = 0.f;
            }
            continue;                            // lmax stays -inf everywhere
        }

        // all lanes load the same address -> single L2 request + broadcast
        const float4 wb = b4[widx];
        if (tid == 0) {
            out[4*r+0] = wb.x; out[4*r+1] = wb.y;
            out[4*r+2] = wb.z; out[4*r+3] = wb.w;
            out[4*MAXOUT + r] = wval;
        }

        const float warea = fmaxf(wb.z - wb.x, 0.f) * fmaxf(wb.w - wb.y, 0.f);

        // ---- fused: suppress vs winner + recompute thread-local argmax ----
        lmax = -INFINITY;
        lidx = 0;
#pragma unroll
        for (int k = 0; k < ITEMS; ++k) {
            const int i = k * THREADS + tid;
            float v = s_sc[i];
            const float ltx = fmaxf(bx1[k], wb.x);
            const float lty = fmaxf(by1[k], wb.y);
            const float rbx = fminf(bx2[k], wb.z);
            const float rby = fminf(by2[k], wb.w);
            const float w  = fmaxf(rbx - ltx, 0.f);
            const float h  = fmaxf(rby - lty, 0.f);
            const float inter = w * h;
            const float area  = fmaxf(bx2[k] - bx1[k], 0.f) * fmaxf(by2[k] - by1[k], 0.f);
            // mirror ref association: ((area_i + area) - inter) + 1e-9
            const float den = ((warea + area) - inter) + 1e-9f;
            const bool supp = inter > IOU_T * den;   // iou > 0.45 (den > 0)
            if (supp) { v = -INFINITY; s_sc[i] = v; }   // winner self-suppresses (iou ~ 1)
            if (v > lmax) { lmax = v; lidx = i; }
        }
    }
}

extern "C" void kernel_launch(void* const* d_in, const int* in_sizes, int n_in,
                              void* d_out, int out_size, void* d_ws, size_t ws_size,
                              hipStream_t stream) {
    const float* boxes  = (const float*)d_in[0];
    const float* scores = (const float*)d_in[1];
    float* out = (float*)d_out;
    nms_kernel<<<dim3(1), dim3(THREADS), 0, stream>>>(boxes, scores, out);
}

// Round 2
// 237.175 us; speedup vs baseline: 4.0387x; 4.0387x over previous
//
#include <hip/hip_runtime.h>
#include <math.h>

#define NB      25200
#define THREADS 512
#define ITEMS   50            // 512*50 = 25600 >= NB
#define NBINS   512
#define CAP     2048
#define IB      (CAP/THREADS) // 4 candidate items per thread
#define MAXOUT  100
#define CONF    0.25f
#define IOU_T   0.45f
#define NWAVE   (THREADS/64)

// lexicographic "is (sb,ib) a better pick than (sa,ia)": higher score, ties -> lower orig index
__device__ __forceinline__ bool better(float sa, int ia, float sb, int ib) {
    return (sb > sa) || (sb == sa && ib < ia);
}

__global__ __launch_bounds__(THREADS, 2)
void nms_kernel(const float* __restrict__ boxes,
                const float* __restrict__ scores,
                float* __restrict__ out)
{
    const int tid  = threadIdx.x;
    const int lane = tid & 63;
    const int wv   = tid >> 6;

    // 102496 B LDS, aliased per phase. Fallback path reuses [0,25600) as live scores.
    __shared__ __align__(16) float smem[25624];
    int*    hist   = (int*)smem;               // [0,512)
    int*    sufs   = (int*)(smem + 512);       // [512,1024)
    float4* cand_b = (float4*)(smem + 2048);   // [2048,10240)  byte off 8192, 16-aligned
    float*  cand_s = smem + 10240;             // [10240,12288)
    int*    cand_i = (int*)(smem + 12288);     // [12288,14336)
    float*  red_v  = smem + 25600;             // [25600,25608)
    int*    red_i  = (int*)(smem + 25608);     // [25608,25616)
    int*    red_s  = (int*)(smem + 25616);     // [25616,25624)
    __shared__ int s_cnt;
    __shared__ int s_t;

    const float4* b4 = (const float4*)boxes;
    const float binscale = (float)NBINS / (1.0f - CONF);

    // ---------------- Phase A1: histogram of scores > CONF ----------------
    hist[tid] = 0;
    if (tid == 0) s_cnt = 0;
    __syncthreads();
    for (int k = 0; k < ITEMS; ++k) {
        const int i = k * THREADS + tid;
        if (i < NB) {
            const float s = scores[i];
            if (s > CONF) {
                int b = (int)((s - CONF) * binscale);
                b = b < 0 ? 0 : (b > NBINS - 1 ? NBINS - 1 : b);
                atomicAdd(&hist[b], 1);
            }
        }
    }
    __syncthreads();

    // ---------------- Phase A2: suffix counts + threshold bin ----------------
    sufs[tid] = hist[tid];
    __syncthreads();
    for (int d = 1; d < NBINS; d <<= 1) {
        const int add = (tid + d < NBINS) ? sufs[tid + d] : 0;
        __syncthreads();
        sufs[tid] += add;
        __syncthreads();
    }
    if (tid == 0) s_t = NBINS;        // default: no bin fits -> empty selection -> fallback
    __syncthreads();
    {
        const int c = sufs[tid];
        if (c <= CAP && (tid == 0 || sufs[tid - 1] > CAP)) s_t = tid;
    }
    __syncthreads();
    const int tbin       = s_t;
    const int total_conf = sufs[0];   // all boxes above CONF

    // ---------------- Phase A3: compact candidates (bin >= tbin) ----------------
    for (int k = 0; k < ITEMS; ++k) {
        const int i = k * THREADS + tid;
        bool pred = false;
        float s = 0.f;
        if (i < NB) {
            s = scores[i];
            if (s > CONF) {
                int b = (int)((s - CONF) * binscale);
                b = b < 0 ? 0 : (b > NBINS - 1 ? NBINS - 1 : b);
                pred = (b >= tbin);
            }
        }
        const unsigned long long m = __ballot(pred);
        if (m) {
            const int ldr = __ffsll(m) - 1;
            int base = 0;
            if (lane == ldr) base = atomicAdd(&s_cnt, __popcll(m));
            base = __shfl(base, ldr);
            if (pred) {
                const int pos = base + __popcll(m & ((1ull << lane) - 1ull));
                if (pos < CAP) {
                    cand_s[pos] = s;
                    cand_i[pos] = i;
                    cand_b[pos] = b4[i];
                }
            }
        }
    }
    __syncthreads();
    const int M = s_cnt;
    const bool overflow = (M > CAP);  // only possible if no valid tbin existed

    // ---------------- Phase B: greedy NMS over candidates ----------------
    int kept = 0;
    if (!overflow) {
        float  ms[IB]; float4 mb[IB]; float ma[IB]; int mi[IB];
        float lmax = -INFINITY; int lidx = 0x7fffffff; int lslot = 0;
#pragma unroll
        for (int k = 0; k < IB; ++k) {
            const int p = k * THREADS + tid;
            if (p < M) { ms[k] = cand_s[p]; mb[k] = cand_b[p]; mi[k] = cand_i[p]; }
            else       { ms[k] = -INFINITY; mb[k] = make_float4(0,0,0,0); mi[k] = 0x7fffffff; }
            ma[k] = fmaxf(mb[k].z - mb[k].x, 0.f) * fmaxf(mb[k].w - mb[k].y, 0.f);
            if (better(lmax, lidx, ms[k], mi[k])) { lmax = ms[k]; lidx = mi[k]; lslot = p; }
        }

        for (int r = 0; r < MAXOUT; ++r) {
            // block argmax of (score, orig idx) carrying slot
            float rv = lmax; int ri = lidx; int rs = lslot;
#pragma unroll
            for (int off = 32; off >= 1; off >>= 1) {
                const float ov = __shfl_xor(rv, off);
                const int   oi = __shfl_xor(ri, off);
                const int   os = __shfl_xor(rs, off);
                if (better(rv, ri, ov, oi)) { rv = ov; ri = oi; rs = os; }
            }
            __syncthreads();                 // prev round's red[] reads complete
            if (lane == 0) { red_v[wv] = rv; red_i[wv] = ri; red_s[wv] = rs; }
            __syncthreads();
            float wval = red_v[0]; int widx = red_i[0]; int wslot = red_s[0];
#pragma unroll
            for (int j = 1; j < NWAVE; ++j) {
                const float v = red_v[j]; const int i2 = red_i[j]; const int s2 = red_s[j];
                if (better(wval, widx, v, i2)) { wval = v; widx = i2; wslot = s2; }
            }

            if (!(wval > -1e38f)) {          // no box left (uniform branch)
                if (tid == 0) {
                    out[4*r+0]=0.f; out[4*r+1]=0.f; out[4*r+2]=0.f; out[4*r+3]=0.f;
                    out[4*MAXOUT + r] = 0.f;
                }
                continue;
            }

            const float4 wb = cand_b[wslot]; // same-address LDS broadcast
            if (tid == 0) {
                out[4*r+0]=wb.x; out[4*r+1]=wb.y; out[4*r+2]=wb.z; out[4*r+3]=wb.w;
                out[4*MAXOUT + r] = wval;
            }
            ++kept;
            const float warea = fmaxf(wb.z - wb.x, 0.f) * fmaxf(wb.w - wb.y, 0.f);

            lmax = -INFINITY; lidx = 0x7fffffff; lslot = 0;
#pragma unroll
            for (int k = 0; k < IB; ++k) {
                const int p = k * THREADS + tid;
                float v = ms[k];
                const float ltx = fmaxf(mb[k].x, wb.x);
                const float lty = fmaxf(mb[k].y, wb.y);
                const float rbx = fminf(mb[k].z, wb.z);
                const float rby = fminf(mb[k].w, wb.w);
                const float w   = fmaxf(rbx - ltx, 0.f);
                const float h   = fmaxf(rby - lty, 0.f);
                const float inter = w * h;
                const float den   = ((warea + ma[k]) - inter) + 1e-9f;
                const bool supp = (inter > IOU_T * den) || (p == wslot); // kill winner explicitly
                if (supp) { v = -INFINITY; ms[k] = v; }
                if (better(lmax, lidx, v, mi[k])) { lmax = v; lidx = mi[k]; lslot = p; }
            }
        }
    }

    // ---------------- Fallback: exact full NMS (never on bench data) ----------------
    if (overflow || (kept < MAXOUT && M < total_conf)) {
        __syncthreads();
        for (int k = 0; k < ITEMS; ++k) {
            const int i = k * THREADS + tid;
            float sc = -INFINITY;
            if (i < NB) { const float s = scores[i]; sc = (s > CONF) ? s : -INFINITY; }
            smem[i] = sc;
        }
        __syncthreads();
        for (int r = 0; r < MAXOUT; ++r) {
            float lm = -INFINITY; int li = 0x7fffffff;
            for (int k = 0; k < ITEMS; ++k) {
                const int i = k * THREADS + tid;
                const float v = smem[i];
                if (v > lm) { lm = v; li = i; }     // ascending i scan: ties -> lower i
            }
            float rv = lm; int ri = li;
#pragma unroll
            for (int off = 32; off >= 1; off >>= 1) {
                const float ov = __shfl_xor(rv, off);
                const int   oi = __shfl_xor(ri, off);
                if (better(rv, ri, ov, oi)) { rv = ov; ri = oi; }
            }
            __syncthreads();
            if (lane == 0) { red_v[wv] = rv; red_i[wv] = ri; }
            __syncthreads();
            float wval = red_v[0]; int widx = red_i[0];
#pragma unroll
            for (int j = 1; j < NWAVE; ++j) {
                const float v = red_v[j]; const int i2 = red_i[j];
                if (better(wval, widx, v, i2)) { wval = v; widx = i2; }
            }
            if (!(wval > -1e38f)) {
                if (tid == 0) {
                    out[4*r+0]=0.f; out[4*r+1]=0.f; out[4*r+2]=0.f; out[4*r+3]=0.f;
                    out[4*MAXOUT + r] = 0.f;
                }
                continue;
            }
            const float4 wb = b4[widx];
            if (tid == 0) {
                out[4*r+0]=wb.x; out[4*r+1]=wb.y; out[4*r+2]=wb.z; out[4*r+3]=wb.w;
                out[4*MAXOUT + r] = wval;
            }
            const float warea = fmaxf(wb.z - wb.x, 0.f) * fmaxf(wb.w - wb.y, 0.f);
            for (int k = 0; k < ITEMS; ++k) {
                const int i = k * THREADS + tid;
                if (i < NB) {
                    const float4 bb = b4[i];
                    const float area = fmaxf(bb.z - bb.x, 0.f) * fmaxf(bb.w - bb.y, 0.f);
                    const float ltx = fmaxf(bb.x, wb.x);
                    const float lty = fmaxf(bb.y, wb.y);
                    const float rbx = fminf(bb.z, wb.z);
                    const float rby = fminf(bb.w, wb.w);
                    const float w  = fmaxf(rbx - ltx, 0.f);
                    const float h  = fmaxf(rby - lty, 0.f);
                    const float inter = w * h;
                    const float den = ((warea + area) - inter) + 1e-9f;
                    if (inter > IOU_T * den || i == widx) smem[i] = -INFINITY;
                }
            }
            __syncthreads();
        }
    }
}

extern "C" void kernel_launch(void* const* d_in, const int* in_sizes, int n_in,
                              void* d_out, int out_size, void* d_ws, size_t ws_size,
                              hipStream_t stream) {
    const float* boxes  = (const float*)d_in[0];
    const float* scores = (const float*)d_in[1];
    float* out = (float*)d_out;
    nms_kernel<<<dim3(1), dim3(THREADS), 0, stream>>>(boxes, scores, out);
}

// Round 3
// 111.661 us; speedup vs baseline: 8.5785x; 2.1241x over previous
//
#include <hip/hip_runtime.h>
#include <math.h>

#define NB      25200
#define NB4     6300          // NB/4 exactly
#define THREADS 512
#define ITEMS   50            // 512*50 = 25600 >= NB
#define NBINS   512
#define CAP     256
#define MAXOUT  100
#define CONF    0.25f
#define IOU_T   0.45f
#define NWAVE   (THREADS/64)

typedef unsigned long long u64;
typedef unsigned int u32;

__device__ __forceinline__ bool better(float sa_, int ia_, float sb_, int ib_) {
    return (sb_ > sa_) || (sb_ == sa_ && ib_ < ia_);
}

__global__ __launch_bounds__(THREADS, 1)
void nms_kernel(const float* __restrict__ boxes,
                const float* __restrict__ scores,
                float* __restrict__ out)
{
    const int tid  = threadIdx.x;
    const int lane = tid & 63;
    const int wv   = tid >> 6;

    // raw scores cache (also fallback live-score array): 25600 floats = 100 KB
    __shared__ float4 smem4[6400];
    float* smem = (float*)smem4;
    __shared__ int    hist[NBINS];
    __shared__ int    sufs[NBINS];
    __shared__ float4 cand_b[CAP];
    __shared__ float  cand_s[CAP];
    __shared__ int    cand_i[CAP];
    __shared__ u64    keys[CAP];
    __shared__ float4 sb[CAP];
    __shared__ float  ss[CAP];
    __shared__ float  sa[CAP];
    __shared__ u64    mat[CAP][4];      // upper-tri suppression bits (j>i only)
    __shared__ int    klist[MAXOUT];
    __shared__ int    s_cnt, s_t, s_kept;
    __shared__ float  red_v[NWAVE];
    __shared__ int    red_i[NWAVE];

    const float4* b4 = (const float4*)boxes;
    const float4* s4 = (const float4*)scores;
    const float binscale = (float)NBINS / (1.0f - CONF);

    // ---------------- init ----------------
    hist[tid] = 0;                         // NBINS == THREADS
    if (tid == 0) { s_cnt = 0; s_t = NBINS; }
    if (tid < 25600 - NB) smem[NB + tid] = -INFINITY;   // pad tail
    __syncthreads();

    // ---------------- A1: scores -> LDS (vectorized) + histogram ----------------
    for (int k = 0; k < 13; ++k) {
        const int v = k * THREADS + tid;
        if (v < NB4) {
            const float4 s = s4[v];
            smem4[v] = s;
            const float el[4] = {s.x, s.y, s.z, s.w};
#pragma unroll
            for (int e = 0; e < 4; ++e) {
                if (el[e] > CONF) {
                    int b = (int)((el[e] - CONF) * binscale);
                    b = b < 0 ? 0 : (b > NBINS - 1 ? NBINS - 1 : b);
                    atomicAdd(&hist[b], 1);
                }
            }
        }
    }
    __syncthreads();

    // ---------------- A2: suffix counts (single wave, barrier-free) ----------------
    if (wv == 0) {
        int h[8], ls[8];
#pragma unroll
        for (int r = 0; r < 8; ++r) h[r] = hist[lane * 8 + r];
        int acc = 0;
#pragma unroll
        for (int r = 7; r >= 0; --r) { acc += h[r]; ls[r] = acc; }
        u32 inc = (u32)acc;                       // inclusive suffix over lane chunks
#pragma unroll
        for (int off = 1; off < 64; off <<= 1) {
            const u32 v = __shfl_down(inc, off);
            if (lane + off < 64) inc += v;
        }
        const int excl = (int)inc - acc;
#pragma unroll
        for (int r = 0; r < 8; ++r) sufs[lane * 8 + r] = ls[r] + excl;
    }
    __syncthreads();
    {
        const int c = sufs[tid];                  // sufs non-increasing -> unique writer
        if (c <= CAP && (tid == 0 || sufs[tid - 1] > CAP)) s_t = tid;
    }
    __syncthreads();
    const int tbin       = s_t;                   // NBINS -> nothing selected -> fallback
    const int total_conf = sufs[0];

    // ---------------- A3: compact candidates (bin >= tbin) from LDS scores ----------------
    for (int k = 0; k < ITEMS; ++k) {
        const int i = k * THREADS + tid;
        const float s = smem[i];
        bool pred = false;
        if (s > CONF) {
            int b = (int)((s - CONF) * binscale);
            b = b < 0 ? 0 : (b > NBINS - 1 ? NBINS - 1 : b);
            pred = (b >= tbin);
        }
        const u64 m = __ballot(pred);
        if (m) {
            const int ldr = __ffsll(m) - 1;
            int base = 0;
            if (lane == ldr) base = atomicAdd(&s_cnt, __popcll(m));
            base = __shfl(base, ldr);
            if (pred) {
                const int pos = base + __popcll(m & ((1ull << lane) - 1ull));
                if (pos < CAP) { cand_s[pos] = s; cand_i[pos] = i; cand_b[pos] = b4[i]; }
            }
        }
    }
    __syncthreads();
    const int M0 = s_cnt;                          // == sufs[tbin] when tbin < NBINS
    const int M  = (M0 > CAP) ? CAP : M0;

    // ---------------- B1: build sort keys ----------------
    // ascending key == score desc, then orig idx asc (stable-argsort tiebreak), slot in low 8
    if (tid < CAP) {
        keys[tid] = (tid < M)
            ? ( ((u64)(~__float_as_uint(cand_s[tid])) << 32)
              | ((u64)(u32)cand_i[tid] << 8) | (u64)tid )
            : ~0ULL;
    }
    __syncthreads();

    // ---------------- B2: bitonic sort 256 keys, single wave (no barriers) ----------------
    if (wv == 0) {
        for (int k = 2; k <= CAP; k <<= 1) {
            for (int j = k >> 1; j >= 1; j >>= 1) {
#pragma unroll
                for (int e = 0; e < 2; ++e) {
                    const int tt = lane + 64 * e;                       // 128 pairs
                    const int i  = ((tt & ~(j - 1)) << 1) | (tt & (j - 1));
                    const int p  = i | j;
                    const bool up = ((i & k) == 0);
                    const u64 a = keys[i], b = keys[p];
                    if (up ? (a > b) : (a < b)) { keys[i] = b; keys[p] = a; }
                }
            }
        }
    }
    __syncthreads();

    // ---------------- B3: gather into sorted order ----------------
    if (tid < CAP) {
        if (tid < M) {
            const int slot = (int)(keys[tid] & 0xFFULL);
            const float4 bb = cand_b[slot];
            sb[tid] = bb;
            ss[tid] = cand_s[slot];
            sa[tid] = fmaxf(bb.z - bb.x, 0.f) * fmaxf(bb.w - bb.y, 0.f);
        } else {
            sb[tid] = make_float4(0.f, 0.f, 0.f, 0.f);
            ss[tid] = 0.f; sa[tid] = 0.f;
        }
    }
    __syncthreads();

    // ---------------- B4: suppression bitmatrix, j > i only ----------------
    for (int task = tid; task < CAP * 4; task += THREADS) {   // 2 word-tasks/thread
        const int i = task >> 2;
        const int w = task & 3;
        u64 bits = 0ULL;
        if (i < M) {
            const float4 bi = sb[i];
            const float  ai = sa[i];
            const int base = w << 6;
            int j0 = i + 1 - base; if (j0 < 0) j0 = 0;
            int j1 = M - base;     if (j1 > 64) j1 = 64;
            for (int jj = j0; jj < j1; ++jj) {
                const float4 bj = sb[base + jj];
                const float ltx = fmaxf(bi.x, bj.x);
                const float lty = fmaxf(bi.y, bj.y);
                const float rbx = fminf(bi.z, bj.z);
                const float rby = fminf(bi.w, bj.w);
                const float w_ = fmaxf(rbx - ltx, 0.f);
                const float h_ = fmaxf(rby - lty, 0.f);
                const float inter = w_ * h_;
                const float den = ((ai + sa[base + jj]) - inter) + 1e-9f;  // ref assoc order
                if (inter > IOU_T * den) bits |= (1ULL << jj);
            }
        }
        mat[i][w] = bits;
    }
    __syncthreads();

    // ---------------- B5: serial greedy bitmask scan (register-resident mask) ----------------
    if (tid == 0) {
        u64 r0 = 0, r1 = 0, r2 = 0, r3 = 0;
        int kept = 0;
        for (int i = 0; i < M; ++i) {
            const int w = i >> 6, b = i & 63;
            const u64 cur = (w == 0) ? r0 : (w == 1) ? r1 : (w == 2) ? r2 : r3;
            if (!((cur >> b) & 1ULL)) {
                klist[kept++] = i;
                if (kept == MAXOUT) break;
                r0 |= mat[i][0]; r1 |= mat[i][1]; r2 |= mat[i][2]; r3 |= mat[i][3];
            }
        }
        s_kept = kept;
    }
    __syncthreads();

    // ---------------- epilogue / fallback decision ----------------
    const int kept = s_kept;
    const bool need_fb = (M0 > CAP) || (kept < MAXOUT && M0 < total_conf);
    if (!need_fb) {                                   // uniform branch
        if (tid < MAXOUT) {
            float4 bb = make_float4(0.f, 0.f, 0.f, 0.f);
            float  sc = 0.f;
            if (tid < kept) { const int j = klist[tid]; bb = sb[j]; sc = ss[j]; }
            out[4*tid+0] = bb.x; out[4*tid+1] = bb.y;
            out[4*tid+2] = bb.z; out[4*tid+3] = bb.w;
            out[4*MAXOUT + tid] = sc;
        }
        return;
    }

    // ---------------- exact full fallback (never on bench data) ----------------
    __syncthreads();
    for (int k = 0; k < ITEMS; ++k) {                 // smem: raw scores -> live scores
        const int i = k * THREADS + tid;
        const float s0 = smem[i];
        smem[i] = (s0 > CONF) ? s0 : -INFINITY;
    }
    __syncthreads();
    for (int r = 0; r < MAXOUT; ++r) {
        float lm = -INFINITY; int li = 0x7fffffff;
        for (int k = 0; k < ITEMS; ++k) {
            const int i = k * THREADS + tid;
            const float v = smem[i];
            if (v > lm) { lm = v; li = i; }           // ascending scan: ties -> lower i
        }
        float rv = lm; int ri = li;
#pragma unroll
        for (int off = 32; off >= 1; off >>= 1) {
            const float ov = __shfl_xor(rv, off);
            const int   oi = __shfl_xor(ri, off);
            if (better(rv, ri, ov, oi)) { rv = ov; ri = oi; }
        }
        __syncthreads();
        if (lane == 0) { red_v[wv] = rv; red_i[wv] = ri; }
        __syncthreads();
        float wval = red_v[0]; int widx = red_i[0];
#pragma unroll
        for (int j = 1; j < NWAVE; ++j) {
            const float v = red_v[j]; const int i2 = red_i[j];
            if (better(wval, widx, v, i2)) { wval = v; widx = i2; }
        }
        if (!(wval > -1e38f)) {
            if (tid == 0) {
                out[4*r+0]=0.f; out[4*r+1]=0.f; out[4*r+2]=0.f; out[4*r+3]=0.f;
                out[4*MAXOUT + r] = 0.f;
            }
            continue;
        }
        const float4 wb = b4[widx];
        if (tid == 0) {
            out[4*r+0]=wb.x; out[4*r+1]=wb.y; out[4*r+2]=wb.z; out[4*r+3]=wb.w;
            out[4*MAXOUT + r] = wval;
        }
        const float warea = fmaxf(wb.z - wb.x, 0.f) * fmaxf(wb.w - wb.y, 0.f);
        for (int k = 0; k < ITEMS; ++k) {
            const int i = k * THREADS + tid;
            if (i < NB) {
                const float4 bb = b4[i];
                const float area = fmaxf(bb.z - bb.x, 0.f) * fmaxf(bb.w - bb.y, 0.f);
                const float ltx = fmaxf(bb.x, wb.x);
                const float lty = fmaxf(bb.y, wb.y);
                const float rbx = fminf(bb.z, wb.z);
                const float rby = fminf(bb.w, wb.w);
                const float w  = fmaxf(rbx - ltx, 0.f);
                const float h  = fmaxf(rby - lty, 0.f);
                const float inter = w * h;
                const float den = ((warea + area) - inter) + 1e-9f;
                if (inter > IOU_T * den || i == widx) smem[i] = -INFINITY;
            }
        }
        __syncthreads();
    }
}

extern "C" void kernel_launch(void* const* d_in, const int* in_sizes, int n_in,
                              void* d_out, int out_size, void* d_ws, size_t ws_size,
                              hipStream_t stream) {
    const float* boxes  = (const float*)d_in[0];
    const float* scores = (const float*)d_in[1];
    float* out = (float*)d_out;
    nms_kernel<<<dim3(1), dim3(THREADS), 0, stream>>>(boxes, scores, out);
}

// Round 4
// 107.227 us; speedup vs baseline: 8.9333x; 1.0414x over previous
//
#include <hip/hip_runtime.h>
#include <math.h>

#define NB      25200
#define NB4     6300          // NB/4 exactly
#define THREADS 512
#define KV      13            // float4 score vectors per thread: 13*512=6656 >= 6300
#define ITEMS   50            // fallback: scalar items per thread (512*50=25600)
#define NBINS   512
#define CAP     256
#define MAXOUT  100
#define CONF    0.25f
#define IOU_T   0.45f
#define NWAVE   (THREADS/64)

typedef unsigned long long u64;
typedef unsigned int u32;

__device__ __forceinline__ bool better(float sa_, int ia_, float sb_, int ib_) {
    return (sb_ > sa_) || (sb_ == sa_ && ib_ < ia_);
}

__global__ __launch_bounds__(THREADS, 1)
void nms_kernel(const float* __restrict__ boxes,
                const float* __restrict__ scores,
                float* __restrict__ out)
{
    const int tid  = threadIdx.x;
    const int lane = tid & 63;
    const int wv   = tid >> 6;

    __shared__ int    hist[NBINS];
    __shared__ int    sufs[NBINS];
    __shared__ float4 cand_b[CAP];
    __shared__ float  cand_s[CAP];
    __shared__ int    cand_i[CAP];
    __shared__ u64    keys[CAP];
    __shared__ float4 sb[CAP];
    __shared__ float  ss[CAP];
    __shared__ float  sa[CAP];
    __shared__ u64    mat[CAP][4];      // upper-tri suppression bits (j>i only)
    __shared__ int    klist[MAXOUT];
    __shared__ int    s_cnt, s_t, s_kept;
    __shared__ float  red_v[NWAVE];
    __shared__ int    red_i[NWAVE];
    __shared__ float  live[25600];      // fallback-only live scores (100 KB)

    const float4* b4 = (const float4*)boxes;
    const float4* s4 = (const float4*)scores;
    const float binscale = (float)NBINS / (1.0f - CONF);

    float4 sc[KV];                      // all scores register-resident

    hist[tid] = 0;                      // NBINS == THREADS
    if (tid == 0) { s_cnt = 0; s_t = NBINS; }
    __syncthreads();

    // ---------------- A1: scores -> registers, histogram from registers ----------------
#pragma unroll
    for (int k = 0; k < KV; ++k) {
        const int v = k * THREADS + tid;
        sc[k] = (v < NB4) ? s4[v] : make_float4(-1.f, -1.f, -1.f, -1.f);
    }
#pragma unroll
    for (int k = 0; k < KV; ++k) {
        const float el[4] = {sc[k].x, sc[k].y, sc[k].z, sc[k].w};
#pragma unroll
        for (int e = 0; e < 4; ++e) {
            if (el[e] > CONF) {
                int b = (int)((el[e] - CONF) * binscale);
                b = b < 0 ? 0 : (b > NBINS - 1 ? NBINS - 1 : b);
                atomicAdd(&hist[b], 1);
            }
        }
    }
    __syncthreads();

    // ---------------- A2: suffix counts (single wave, barrier-free) ----------------
    if (wv == 0) {
        int h[8], ls[8];
#pragma unroll
        for (int r = 0; r < 8; ++r) h[r] = hist[lane * 8 + r];
        int acc = 0;
#pragma unroll
        for (int r = 7; r >= 0; --r) { acc += h[r]; ls[r] = acc; }
        u32 inc = (u32)acc;
#pragma unroll
        for (int off = 1; off < 64; off <<= 1) {
            const u32 v = __shfl_down(inc, off);
            if (lane + off < 64) inc += v;
        }
        const int excl = (int)inc - acc;
#pragma unroll
        for (int r = 0; r < 8; ++r) sufs[lane * 8 + r] = ls[r] + excl;
    }
    __syncthreads();
    {
        const int c = sufs[tid];                  // non-increasing -> unique writer
        if (c <= CAP && (tid == 0 || sufs[tid - 1] > CAP)) s_t = tid;
    }
    __syncthreads();
    const int tbin       = s_t;                   // NBINS -> nothing selected -> fallback
    const int total_conf = sufs[0];

    // ---------------- A3: compact candidates (bin >= tbin) from registers ----------------
#pragma unroll
    for (int k = 0; k < KV; ++k) {
        const int v = k * THREADS + tid;
        const float el[4] = {sc[k].x, sc[k].y, sc[k].z, sc[k].w};
#pragma unroll
        for (int e = 0; e < 4; ++e) {
            const float s = el[e];
            bool pred = false;
            if (s > CONF) {
                int b = (int)((s - CONF) * binscale);
                b = b < 0 ? 0 : (b > NBINS - 1 ? NBINS - 1 : b);
                pred = (b >= tbin);
            }
            const u64 m = __ballot(pred);
            if (m) {
                const int ldr = __ffsll(m) - 1;
                int base = 0;
                if (lane == ldr) base = atomicAdd(&s_cnt, __popcll(m));
                base = __shfl(base, ldr);
                if (pred) {
                    const int pos = base + __popcll(m & ((1ull << lane) - 1ull));
                    if (pos < CAP) {
                        const int i = 4 * v + e;
                        cand_s[pos] = s; cand_i[pos] = i; cand_b[pos] = b4[i];
                    }
                }
            }
        }
    }
    __syncthreads();
    const int M0 = s_cnt;
    const int M  = (M0 > CAP) ? CAP : M0;

    // ---------------- B1: sort keys (score desc, orig idx asc) ----------------
    if (tid < CAP) {
        keys[tid] = (tid < M)
            ? (((u64)(~__float_as_uint(cand_s[tid])) << 32) | (u64)(u32)cand_i[tid])
            : (0xFFFFFFFF00000000ULL | (u64)tid);   // distinct, after all real keys
    }
    __syncthreads();

    // ---------------- B2: rank by counting (parallel, broadcast reads) ----------------
    if (tid < CAP) {
        const u64 mykey = keys[tid];
        int rank = 0;
#pragma unroll 8
        for (int j = 0; j < CAP; ++j) rank += (keys[j] < mykey) ? 1 : 0;
        if (tid < M) {                            // real keys rank < M (distinct keys)
            const float4 bb = cand_b[tid];
            sb[rank] = bb;
            ss[rank] = cand_s[tid];
            sa[rank] = fmaxf(bb.z - bb.x, 0.f) * fmaxf(bb.w - bb.y, 0.f);
        }
    }
    __syncthreads();

    // ---------------- B4: suppression bitmatrix, j > i only ----------------
    for (int task = tid; task < CAP * 4; task += THREADS) {
        const int i = task >> 2;
        const int w = task & 3;
        u64 bits = 0ULL;
        if (i < M) {
            const float4 bi = sb[i];
            const float  ai = sa[i];
            const int base = w << 6;
            int j0 = i + 1 - base; if (j0 < 0) j0 = 0;
            int j1 = M - base;     if (j1 > 64) j1 = 64;
            for (int jj = j0; jj < j1; ++jj) {
                const float4 bj = sb[base + jj];
                const float ltx = fmaxf(bi.x, bj.x);
                const float lty = fmaxf(bi.y, bj.y);
                const float rbx = fminf(bi.z, bj.z);
                const float rby = fminf(bi.w, bj.w);
                const float w_ = fmaxf(rbx - ltx, 0.f);
                const float h_ = fmaxf(rby - lty, 0.f);
                const float inter = w_ * h_;
                const float den = ((ai + sa[base + jj]) - inter) + 1e-9f;  // ref assoc order
                if (inter > IOU_T * den) bits |= (1ULL << jj);
            }
        }
        mat[i][w] = bits;
    }
    __syncthreads();

    // ---------------- B5: serial greedy scan, 8-row prefetch groups ----------------
    if (tid == 0) {
        u64 r0 = 0, r1 = 0, r2 = 0, r3 = 0;
        int kept = 0;
        for (int base = 0; base < M && kept < MAXOUT; base += 8) {
            u64 rw[8][4];
#pragma unroll
            for (int q = 0; q < 8; ++q) {
#pragma unroll
                for (int w = 0; w < 4; ++w) rw[q][w] = mat[base + q][w];  // batched reads
            }
#pragma unroll
            for (int q = 0; q < 8; ++q) {
                const int i = base + q;
                if (i >= M || kept >= MAXOUT) break;
                const int w = i >> 6, b = i & 63;
                const u64 cur = (w == 0) ? r0 : (w == 1) ? r1 : (w == 2) ? r2 : r3;
                if (!((cur >> b) & 1ULL)) {
                    klist[kept++] = i;
                    if (kept == MAXOUT) break;
                    r0 |= rw[q][0]; r1 |= rw[q][1]; r2 |= rw[q][2]; r3 |= rw[q][3];
                }
            }
        }
        s_kept = kept;
    }
    __syncthreads();

    // ---------------- epilogue / fallback decision ----------------
    const int kept = s_kept;
    const bool need_fb = (M0 > CAP) || (kept < MAXOUT && M0 < total_conf);
    if (!need_fb) {                                   // uniform branch
        if (tid < MAXOUT) {
            float4 bb = make_float4(0.f, 0.f, 0.f, 0.f);
            float  sc_ = 0.f;
            if (tid < kept) { const int j = klist[tid]; bb = sb[j]; sc_ = ss[j]; }
            out[4*tid+0] = bb.x; out[4*tid+1] = bb.y;
            out[4*tid+2] = bb.z; out[4*tid+3] = bb.w;
            out[4*MAXOUT + tid] = sc_;
        }
        return;
    }

    // ---------------- exact full fallback (never on bench data) ----------------
    if (tid < 25600 - NB) live[NB + tid] = -INFINITY;
#pragma unroll
    for (int k = 0; k < KV; ++k) {
        const int v = k * THREADS + tid;
        if (v < NB4) {
            const float el[4] = {sc[k].x, sc[k].y, sc[k].z, sc[k].w};
#pragma unroll
            for (int e = 0; e < 4; ++e) {
                const int i = 4 * v + e;
                live[i] = (el[e] > CONF) ? el[e] : -INFINITY;
            }
        }
    }
    __syncthreads();
    for (int r = 0; r < MAXOUT; ++r) {
        float lm = -INFINITY; int li = 0x7fffffff;
        for (int k = 0; k < ITEMS; ++k) {
            const int i = k * THREADS + tid;
            const float v = live[i];
            if (v > lm) { lm = v; li = i; }           // ascending scan: ties -> lower i
        }
        float rv = lm; int ri = li;
#pragma unroll
        for (int off = 32; off >= 1; off >>= 1) {
            const float ov = __shfl_xor(rv, off);
            const int   oi = __shfl_xor(ri, off);
            if (better(rv, ri, ov, oi)) { rv = ov; ri = oi; }
        }
        __syncthreads();
        if (lane == 0) { red_v[wv] = rv; red_i[wv] = ri; }
        __syncthreads();
        float wval = red_v[0]; int widx = red_i[0];
#pragma unroll
        for (int j = 1; j < NWAVE; ++j) {
            const float v = red_v[j]; const int i2 = red_i[j];
            if (better(wval, widx, v, i2)) { wval = v; widx = i2; }
        }
        if (!(wval > -1e38f)) {
            if (tid == 0) {
                out[4*r+0]=0.f; out[4*r+1]=0.f; out[4*r+2]=0.f; out[4*r+3]=0.f;
                out[4*MAXOUT + r] = 0.f;
            }
            continue;
        }
        const float4 wb = b4[widx];
        if (tid == 0) {
            out[4*r+0]=wb.x; out[4*r+1]=wb.y; out[4*r+2]=wb.z; out[4*r+3]=wb.w;
            out[4*MAXOUT + r] = wval;
        }
        const float warea = fmaxf(wb.z - wb.x, 0.f) * fmaxf(wb.w - wb.y, 0.f);
        for (int k = 0; k < ITEMS; ++k) {
            const int i = k * THREADS + tid;
            if (i < NB) {
                const float4 bb = b4[i];
                const float area = fmaxf(bb.z - bb.x, 0.f) * fmaxf(bb.w - bb.y, 0.f);
                const float ltx = fmaxf(bb.x, wb.x);
                const float lty = fmaxf(bb.y, wb.y);
                const float rbx = fminf(bb.z, wb.z);
                const float rby = fminf(bb.w, wb.w);
                const float w  = fmaxf(rbx - ltx, 0.f);
                const float h  = fmaxf(rby - lty, 0.f);
                const float inter = w * h;
                const float den = ((warea + area) - inter) + 1e-9f;
                if (inter > IOU_T * den || i == widx) live[i] = -INFINITY;
            }
        }
        __syncthreads();
    }
}

extern "C" void kernel_launch(void* const* d_in, const int* in_sizes, int n_in,
                              void* d_out, int out_size, void* d_ws, size_t ws_size,
                              hipStream_t stream) {
    const float* boxes  = (const float*)d_in[0];
    const float* scores = (const float*)d_in[1];
    float* out = (float*)d_out;
    nms_kernel<<<dim3(1), dim3(THREADS), 0, stream>>>(boxes, scores, out);
}

// Round 5
// 98.997 us; speedup vs baseline: 9.6759x; 1.0831x over previous
//
#include <hip/hip_runtime.h>
#include <math.h>

#define NB      25200
#define NB4     6300          // NB/4 exactly
#define NBINS   512
#define CAP     256
#define MAXOUT  100
#define CONF    0.25f
#define IOU_T   0.45f
#define ITEMS   50            // fallback: scalar items per 512-thread block
#define NWAVE   8

typedef unsigned long long u64;
typedef unsigned int u32;

__device__ __forceinline__ bool better(float sa_, int ia_, float sb_, int ib_) {
    return (sb_ > sa_) || (sb_ == sa_ && ib_ < ia_);
}

// ---------------- K1: global histogram of scores > CONF ----------------
__global__ __launch_bounds__(128, 1)
void k_hist(const float* __restrict__ scores, int* __restrict__ hist)
{
    const int v = blockIdx.x * 128 + threadIdx.x;
    if (v < NB4) {
        const float4 s = ((const float4*)scores)[v];
        const float binscale = (float)NBINS / (1.0f - CONF);
        const float el[4] = {s.x, s.y, s.z, s.w};
#pragma unroll
        for (int e = 0; e < 4; ++e) {
            if (el[e] > CONF) {
                int b = (int)((el[e] - CONF) * binscale);
                b = b < 0 ? 0 : (b > NBINS - 1 ? NBINS - 1 : b);
                atomicAdd(&hist[b], 1);
            }
        }
    }
}

// ---------------- K2: per-block threshold + distributed compaction ----------------
__global__ __launch_bounds__(128, 1)
void k_compact(const float* __restrict__ scores, const float* __restrict__ boxes,
               const int* __restrict__ hist, int* __restrict__ cnt,
               float* __restrict__ cand_s, int* __restrict__ cand_i,
               float4* __restrict__ cand_b, int* __restrict__ misc)
{
    const int tid = threadIdx.x, lane = tid & 63, wv = tid >> 6, bid = blockIdx.x;
    __shared__ int s_tbin;
    const float binscale = (float)NBINS / (1.0f - CONF);

    // prefetch this block's score slice early (overlaps wave-0 scan)
    const int v = bid * 99 + tid;
    float4 s = make_float4(-1.f, -1.f, -1.f, -1.f);
    if (tid < 99 && v < NB4) s = ((const float4*)scores)[v];

    if (wv == 0) {
        const int4* h4 = (const int4*)hist;
        const int4 a = h4[lane * 2], b = h4[lane * 2 + 1];
        const int h[8] = {a.x, a.y, a.z, a.w, b.x, b.y, b.z, b.w};
        int ls[8]; int acc = 0;
#pragma unroll
        for (int r = 7; r >= 0; --r) { acc += h[r]; ls[r] = acc; }
        u32 inc = (u32)acc;                       // inclusive suffix over lane chunks
#pragma unroll
        for (int off = 1; off < 64; off <<= 1) {
            const u32 t = __shfl_down(inc, off);
            if (lane + off < 64) inc += t;
        }
        const int excl = (int)inc - acc;
        int loc = NBINS;                          // smallest bin with suffix <= CAP
#pragma unroll
        for (int r = 7; r >= 0; --r) { if (ls[r] + excl <= CAP) loc = lane * 8 + r; }
#pragma unroll
        for (int off = 32; off >= 1; off >>= 1) {
            const int t = __shfl_xor(loc, off);
            if (t < loc) loc = t;
        }
        const int total = (int)__shfl(inc, 0);    // sufs[0] = total above CONF
        if (lane == 0) {
            s_tbin = loc;
            if (bid == 0) { misc[0] = total; misc[1] = loc; }
        }
    }
    __syncthreads();
    const int tbin = s_tbin;

    const float4* b4 = (const float4*)boxes;
    const float el[4] = {s.x, s.y, s.z, s.w};
#pragma unroll
    for (int e = 0; e < 4; ++e) {
        const float sv = el[e];
        bool pred = false;
        if (sv > CONF) {
            int b = (int)((sv - CONF) * binscale);
            b = b < 0 ? 0 : (b > NBINS - 1 ? NBINS - 1 : b);
            pred = (b >= tbin);
        }
        const u64 m = __ballot(pred);
        if (m) {
            const int ldr = __ffsll(m) - 1;
            int base = 0;
            if (lane == ldr) base = atomicAdd(cnt, __popcll(m));
            base = __shfl(base, ldr);
            if (pred) {
                const int pos = base + __popcll(m & ((1ull << lane) - 1ull));
                if (pos < CAP) {
                    const int i = 4 * v + e;
                    cand_s[pos] = sv; cand_i[pos] = i; cand_b[pos] = b4[i];
                }
            }
        }
    }
}

// ---------------- K3: sort + bitmatrix + greedy scan (+ exact fallback) ----------------
__global__ __launch_bounds__(512, 1)
void k_nms(const float* __restrict__ boxes, const float* __restrict__ scores,
           const int* __restrict__ cnt, const float* __restrict__ cand_s,
           const int* __restrict__ cand_i, const float4* __restrict__ cand_b,
           const int* __restrict__ misc, float* __restrict__ out)
{
    const int tid  = threadIdx.x;
    const int lane = tid & 63;
    const int wv   = tid >> 6;

    __shared__ u64    keys[CAP];
    __shared__ float4 sb[CAP];
    __shared__ float  ss[CAP];
    __shared__ float  sa[CAP];
    __shared__ u64    mat[CAP][4];
    __shared__ int    klist[MAXOUT];
    __shared__ int    s_kept;
    __shared__ float  red_v[NWAVE];
    __shared__ int    red_i[NWAVE];
    __shared__ float  live[25600];      // fallback only (100 KB)

    // early loads
    const int M0 = *cnt;
    const int total_conf = misc[0];
    const int M  = (M0 > CAP) ? CAP : M0;
    float  cs = 0.f; int ci = 0; float4 cb = make_float4(0.f, 0.f, 0.f, 0.f);
    if (tid < CAP && tid < M) { cs = cand_s[tid]; ci = cand_i[tid]; cb = cand_b[tid]; }

    // B1: sort keys (score desc, orig idx asc); sentinels distinct & larger than any real key
    if (tid < CAP) {
        keys[tid] = (tid < M)
            ? (((u64)(~__float_as_uint(cs)) << 32) | (u64)(u32)ci)
            : (0xFFFFFFFF00000000ULL | (u64)tid);
    }
    __syncthreads();

    // B2: rank by counting (broadcast LDS reads), scatter into sorted order
    if (tid < CAP) {
        const u64 mykey = keys[tid];
        int rank = 0;
#pragma unroll 8
        for (int j = 0; j < CAP; ++j) rank += (keys[j] < mykey) ? 1 : 0;
        if (tid < M) {
            sb[rank] = cb;
            ss[rank] = cs;
            sa[rank] = fmaxf(cb.z - cb.x, 0.f) * fmaxf(cb.w - cb.y, 0.f);
        }
    }
    __syncthreads();

    // B4: suppression bitmatrix, j > i only
    for (int task = tid; task < CAP * 4; task += 512) {
        const int i = task >> 2;
        const int w = task & 3;
        u64 bits = 0ULL;
        if (i < M) {
            const float4 bi = sb[i];
            const float  ai = sa[i];
            const int base = w << 6;
            int j0 = i + 1 - base; if (j0 < 0) j0 = 0;
            int j1 = M - base;     if (j1 > 64) j1 = 64;
            for (int jj = j0; jj < j1; ++jj) {
                const float4 bj = sb[base + jj];
                const float ltx = fmaxf(bi.x, bj.x);
                const float lty = fmaxf(bi.y, bj.y);
                const float rbx = fminf(bi.z, bj.z);
                const float rby = fminf(bi.w, bj.w);
                const float w_ = fmaxf(rbx - ltx, 0.f);
                const float h_ = fmaxf(rby - lty, 0.f);
                const float inter = w_ * h_;
                const float den = ((ai + sa[base + jj]) - inter) + 1e-9f;  // ref assoc order
                if (inter > IOU_T * den) bits |= (1ULL << jj);
            }
        }
        mat[i][w] = bits;
    }
    __syncthreads();

    // B5: serial greedy scan, 8-row prefetch groups
    if (tid == 0) {
        u64 r0 = 0, r1 = 0, r2 = 0, r3 = 0;
        int kept = 0;
        for (int base = 0; base < M && kept < MAXOUT; base += 8) {
            u64 rw[8][4];
#pragma unroll
            for (int q = 0; q < 8; ++q)
#pragma unroll
                for (int w = 0; w < 4; ++w) rw[q][w] = mat[base + q][w];
#pragma unroll
            for (int q = 0; q < 8; ++q) {
                const int i = base + q;
                if (i >= M || kept >= MAXOUT) break;
                const int w = i >> 6, b = i & 63;
                const u64 cur = (w == 0) ? r0 : (w == 1) ? r1 : (w == 2) ? r2 : r3;
                if (!((cur >> b) & 1ULL)) {
                    klist[kept++] = i;
                    if (kept == MAXOUT) break;
                    r0 |= rw[q][0]; r1 |= rw[q][1]; r2 |= rw[q][2]; r3 |= rw[q][3];
                }
            }
        }
        s_kept = kept;
    }
    __syncthreads();

    const int kept = s_kept;
    const bool need_fb = (M0 > CAP) || (kept < MAXOUT && M0 < total_conf);
    if (!need_fb) {                                   // uniform branch
        if (tid < MAXOUT) {
            float4 bb = make_float4(0.f, 0.f, 0.f, 0.f);
            float  sc_ = 0.f;
            if (tid < kept) { const int j = klist[tid]; bb = sb[j]; sc_ = ss[j]; }
            out[4*tid+0] = bb.x; out[4*tid+1] = bb.y;
            out[4*tid+2] = bb.z; out[4*tid+3] = bb.w;
            out[4*MAXOUT + tid] = sc_;
        }
        return;
    }

    // ---------------- exact full fallback (never on bench data) ----------------
    const float4* b4 = (const float4*)boxes;
    for (int k = 0; k < ITEMS; ++k) {
        const int i = k * 512 + tid;
        float sc0 = -INFINITY;
        if (i < NB) { const float s0 = scores[i]; sc0 = (s0 > CONF) ? s0 : -INFINITY; }
        live[i] = sc0;
    }
    __syncthreads();
    for (int r = 0; r < MAXOUT; ++r) {
        float lm = -INFINITY; int li = 0x7fffffff;
        for (int k = 0; k < ITEMS; ++k) {
            const int i = k * 512 + tid;
            const float v = live[i];
            if (v > lm) { lm = v; li = i; }           // ascending scan: ties -> lower i
        }
        float rv = lm; int ri = li;
#pragma unroll
        for (int off = 32; off >= 1; off >>= 1) {
            const float ov = __shfl_xor(rv, off);
            const int   oi = __shfl_xor(ri, off);
            if (better(rv, ri, ov, oi)) { rv = ov; ri = oi; }
        }
        __syncthreads();
        if (lane == 0) { red_v[wv] = rv; red_i[wv] = ri; }
        __syncthreads();
        float wval = red_v[0]; int widx = red_i[0];
#pragma unroll
        for (int j = 1; j < NWAVE; ++j) {
            const float v = red_v[j]; const int i2 = red_i[j];
            if (better(wval, widx, v, i2)) { wval = v; widx = i2; }
        }
        if (!(wval > -1e38f)) {
            if (tid == 0) {
                out[4*r+0]=0.f; out[4*r+1]=0.f; out[4*r+2]=0.f; out[4*r+3]=0.f;
                out[4*MAXOUT + r] = 0.f;
            }
            continue;
        }
        const float4 wb = b4[widx];
        if (tid == 0) {
            out[4*r+0]=wb.x; out[4*r+1]=wb.y; out[4*r+2]=wb.z; out[4*r+3]=wb.w;
            out[4*MAXOUT + r] = wval;
        }
        const float warea = fmaxf(wb.z - wb.x, 0.f) * fmaxf(wb.w - wb.y, 0.f);
        for (int k = 0; k < ITEMS; ++k) {
            const int i = k * 512 + tid;
            if (i < NB) {
                const float4 bb = b4[i];
                const float area = fmaxf(bb.z - bb.x, 0.f) * fmaxf(bb.w - bb.y, 0.f);
                const float ltx = fmaxf(bb.x, wb.x);
                const float lty = fmaxf(bb.y, wb.y);
                const float rbx = fminf(bb.z, wb.z);
                const float rby = fminf(bb.w, wb.w);
                const float w  = fmaxf(rbx - ltx, 0.f);
                const float h  = fmaxf(rby - lty, 0.f);
                const float inter = w * h;
                const float den = ((warea + area) - inter) + 1e-9f;
                if (inter > IOU_T * den || i == widx) live[i] = -INFINITY;
            }
        }
        __syncthreads();
    }
}

extern "C" void kernel_launch(void* const* d_in, const int* in_sizes, int n_in,
                              void* d_out, int out_size, void* d_ws, size_t ws_size,
                              hipStream_t stream) {
    const float* boxes  = (const float*)d_in[0];
    const float* scores = (const float*)d_in[1];
    float* out = (float*)d_out;
    char* ws = (char*)d_ws;
    int*    hist   = (int*)ws;               // [0, 2048)
    int*    cnt    = (int*)(ws + 2048);      // [2048, 2052)
    int*    misc   = (int*)(ws + 2056);      // [2056, 2064)  {total_conf, tbin}
    float*  cand_s = (float*)(ws + 2112);    // [2112, 3136)
    int*    cand_i = (int*)(ws + 3136);      // [3136, 4160)
    float4* cand_b = (float4*)(ws + 4224);   // [4224, 8320)  16B-aligned

    hipMemsetAsync(ws, 0, 2064, stream);
    k_hist   <<<dim3(50), dim3(128), 0, stream>>>(scores, hist);
    k_compact<<<dim3(64), dim3(128), 0, stream>>>(scores, boxes, hist, cnt,
                                                  cand_s, cand_i, cand_b, misc);
    k_nms    <<<dim3(1),  dim3(512), 0, stream>>>(boxes, scores, cnt,
                                                  cand_s, cand_i, cand_b, misc, out);
}